// Round 5
// baseline (252.109 us; speedup 1.0000x reference)
//
#include <hip/hip_runtime.h>

#define NN 500
#define SLOPEC 0.01f

typedef unsigned short us;
typedef unsigned int u32;
typedef unsigned long long u64;

// ---- scratch between dispatches (fp32, 16B-aligned) ----
// No fp32 input copies anymore: every consumer converts bf16->f32 inline at
// load time (exact b2f). All scratch below is fully rewritten every launch:
// no zeroing, no atomics -> graph-replay safe.
__device__ __align__(16) float g_cfw[NN*128];
__device__ __align__(16) float g_Yw[NN*128];
__device__ __align__(16) float g_Zw[NN*128];
__device__ __align__(16) float g_logA[4000];   // exp(-dist) numerators
__device__ __align__(16) float g_logB[4000];
__device__ int   g_inds[4000];
__device__ int   g_inds_tc[4000];
__device__ __align__(16) float g_bsumA[128];   // per-KNN-block denominator partials
__device__ __align__(16) float g_bsumB[128];   // (125 used each; deterministic stores)

__device__ __forceinline__ float b2f(us u){ return __uint_as_float(((u32)u)<<16); }
__device__ __forceinline__ us f2b(float f){
  u32 u = __float_as_uint(f);
  u32 r = u + 0x7fffu + ((u>>16)&1u);
  return (us)(r>>16);
}
__device__ __forceinline__ float lrelu(float x){ return x >= 0.f ? x : SLOPEC*x; }
__device__ __forceinline__ int clampi(int v){ return v < 0 ? 0 : (v >= NN ? NN-1 : v); }

// Inline dtype-dispatched load. Uniform flag -> compiler keeps the branch
// (cannot speculate unknown-dereferenceable loads); precedent: k0's CVT macro
// ran this exact pattern for 5 rounds.
__device__ __forceinline__ float ldin(const void* p, int i, int f){
  return f ? ((const float*)p)[i] : b2f(((const us*)p)[i]);
}
// dot4 with inline-converted weight loads; accumulation order identical to the
// proven float4 dot4 (w0*h0 + w1*h1 + w2*h2 + w3*h3, left to right).
__device__ __forceinline__ float dot4i(const void* w, int base, const float* h, int f){
  return ldin(w,base,f)*h[0] + ldin(w,base+1,f)*h[1]
       + ldin(w,base+2,f)*h[2] + ldin(w,base+3,f)*h[3];
}
// per-block dtype detect from img_feat bit patterns (cheap: 512 us loads)
__device__ __forceinline__ int detect_f32(const void* in0, int tid, int* sflag){
  if (tid < 64){
    const us* u = (const us*)in0;
    int cnt = 0;
    #pragma unroll
    for (int j = 0; j < 8; ++j){
      us v = u[2*(tid*8+j)];          // even us-index: fp32 low-halves if fp32
      int e = (v >> 7) & 0xff;
      cnt += (e >= 143);              // |x| >= 2^16 as bf16: impossible for real data
    }
    #pragma unroll
    for (int off = 32; off; off >>= 1) cnt += __shfl_xor(cnt, off);
    if (tid == 0) *sflag = (cnt > 16);
  }
  __syncthreads();
  return *sflag;
}

// kA: blocks 0..249   = KNN (1 query/wave, 4/block) + exp(-dist) + denom partial store.
//     blocks 250..749 = per-point conv chains (ONE point per block, round-0-proven
//                       parallelism), all inputs converted inline.
__global__ __launch_bounds__(256) void kA(
    const void* imf, const void* cc, const void* ct,
    const void* wc1, const void* bc1, const void* wc2, const void* bc2,
    const void* wps1, const void* bps1, const void* wps2, const void* bps2,
    const void* wp1, const void* bp1, const void* wp2, const void* bp2)
{
  __shared__ __align__(16) float sm[1504];
  __shared__ float s_wsum[4];
  __shared__ int sflag;
  const int tid = threadIdx.x;
  const int b = blockIdx.x;
  const int f = detect_f32(imf, tid, &sflag);

  if (b < 250) {
    // ---------------- KNN + exp numerators (proven path, inline-convert) ----------------
    const int dir = (b >= 125);            // 0: query=c, ref=ct ; 1: query=ct, ref=c
    const void* refp = dir ? cc : ct;
    const void* qp   = dir ? ct : cc;
    int* outp = dir ? g_inds_tc : g_inds;
    float* logp = dir ? g_logB : g_logA;
    for (int e = tid; e < 1500; e += 256) sm[e] = ldin(refp, e, f);
    __syncthreads();
    const int lane = tid & 63;
    const int wv = tid >> 6;
    const int q = b*4 + wv;
    const int qi = q - (dir ? 500 : 0);
    float qx = ldin(qp, qi*3+0, f), qy = ldin(qp, qi*3+1, f), qz = ldin(qp, qi*3+2, f);
    // exact numpy op order: sum(q^2) - 2*dot + sum(r^2)
    float sq = __fadd_rn(__fadd_rn(__fmul_rn(qx,qx),__fmul_rn(qy,qy)),__fmul_rn(qz,qz));
    const u64 SENT = 0xFFFFFFFF00000000ull;   // sentinel carries valid idx 0
    u64 a0=SENT,a1=SENT,a2=SENT,a3=SENT,a4=SENT,a5=SENT,a6=SENT,a7=SENT;
    for (int j = lane; j < NN; j += 64){
      float rx = sm[j*3+0], ry = sm[j*3+1], rz = sm[j*3+2];
      float dt = __fadd_rn(__fadd_rn(__fmul_rn(qx,rx),__fmul_rn(qy,ry)),__fmul_rn(qz,rz));
      float sr = __fadd_rn(__fadd_rn(__fmul_rn(rx,rx),__fmul_rn(ry,ry)),__fmul_rn(rz,rz));
      float d2 = __fadd_rn(__fsub_rn(sq, __fmul_rn(2.f,dt)), sr);
      u32 fb = __float_as_uint(d2);
      fb = (fb & 0x80000000u) ? ~fb : (fb | 0x80000000u);   // monotone float->uint
      u64 key = ((u64)fb << 32) | (u32)j;
      if (key < a0){ u64 t=a0; a0=key; key=t; }
      if (key < a1){ u64 t=a1; a1=key; key=t; }
      if (key < a2){ u64 t=a2; a2=key; key=t; }
      if (key < a3){ u64 t=a3; a3=key; key=t; }
      if (key < a4){ u64 t=a4; a4=key; key=t; }
      if (key < a5){ u64 t=a5; a5=key; key=t; }
      if (key < a6){ u64 t=a6; a6=key; key=t; }
      if (key < a7){ u64 t=a7; a7=key; key=t; }
    }
    float wsum = 0.f;
    #pragma unroll
    for (int r8 = 0; r8 < 8; ++r8){
      u64 m = a0;
      #pragma unroll
      for (int off = 32; off; off >>= 1){
        u64 o = __shfl_xor(m, off);
        if (o < m) m = o;
      }
      bool mine = (a0 == m);
      a0 = mine ? a1 : a0;  a1 = mine ? a2 : a1;  a2 = mine ? a3 : a2;
      a3 = mine ? a4 : a3;  a4 = mine ? a5 : a4;  a5 = mine ? a6 : a5;
      a6 = mine ? a7 : a6;  a7 = mine ? SENT : a7;
      if (lane == 0){
        int idx = (int)(m & 0xffffffffu);
        outp[qi*8 + r8] = idx;
        // softmax numerator exp(-dist), reference dist order
        float rx = sm[idx*3+0], ry = sm[idx*3+1], rz = sm[idx*3+2];
        float dx = __fsub_rn(qx,rx), dy = __fsub_rn(qy,ry), dz = __fsub_rn(qz,rz);
        float s2 = __fadd_rn(__fadd_rn(__fmul_rn(dx,dx),__fmul_rn(dy,dy)),__fmul_rn(dz,dz));
        float v = expf(-sqrtf(s2));   // in [4.5e-5,1]: shift-free safe
        logp[qi*8 + r8] = v;
        wsum += v;
      }
    }
    if (lane == 0) s_wsum[wv] = wsum;
    __syncthreads();
    if (tid == 0){
      float bs = (s_wsum[0] + s_wsum[1]) + (s_wsum[2] + s_wsum[3]);
      (dir ? g_bsumB : g_bsumA)[dir ? (b-125) : b] = bs;   // plain store, no atomic
    }
  } else {
    // ---------------- per-point conv chain, ONE point per block ----------------
    const int p = b - 250;
    float* sx  = sm;          // 3   (c column)
    float* sxi = sm + 4;      // 32  (imf column)
    float* h1  = sm + 64;     // 64
    float* cf  = sm + 128;    // 128
    float* h2  = sm + 256;    // 256
    float* hy  = sm + 512;    // 64
    if (tid < 3)  sx[tid] = ldin(cc, p*3 + tid, f);
    if (tid >= 32 && tid < 64) sxi[tid-32] = ldin(imf, (tid-32)*NN + p, f);
    __syncthreads();
    // stage1: h1 = lrelu(pconv1 @ x + b)   (threads 0..63)
    if (tid < 64){
      float acc = ldin(bp1, tid, f);
      acc += ldin(wp1, tid*3+0, f)*sx[0];
      acc += ldin(wp1, tid*3+1, f)*sx[1];
      acc += ldin(wp1, tid*3+2, f)*sx[2];
      h1[tid] = lrelu(acc);
    }
    __syncthreads();
    // stage2 (t0..127): cf = pconv2 @ h1 + b  (dot64, 2 acc)
    // stage5 (t128..191): hy = lrelu(conv1 @ imf + b)  (dot32, 2 acc)
    if (tid < 128){
      int r = tid;
      float aA = ldin(bp2, r, f), aB = 0.f;
      #pragma unroll 8
      for (int c4=0; c4<16; c4+=2){
        aA += dot4i(wp2, r*64 + c4*4,     h1 + c4*4,     f);
        aB += dot4i(wp2, r*64 + (c4+1)*4, h1 + c4*4 + 4, f);
      }
      float acc = aA + aB;
      cf[r] = acc;
      g_cfw[(size_t)p*128 + r] = acc;
    } else if (tid < 192){
      int r = tid - 128;
      float aA = ldin(bc1, r, f), aB = 0.f;
      #pragma unroll 4
      for (int c4=0; c4<8; c4+=2){
        aA += dot4i(wc1, r*32 + c4*4,     sxi + c4*4,     f);
        aB += dot4i(wc1, r*32 + (c4+1)*4, sxi + c4*4 + 4, f);
      }
      hy[r] = lrelu(aA + aB);
    }
    __syncthreads();
    // stage3 (all 256): h2 = lrelu(psconv1 @ cf + b)  (dot128, 2 acc)
    {
      float aA = ldin(bps1, tid, f), aB = 0.f;
      #pragma unroll 8
      for (int c4=0; c4<32; c4+=2){
        aA += dot4i(wps1, tid*128 + c4*4,     cf + c4*4,     f);
        aB += dot4i(wps1, tid*128 + (c4+1)*4, cf + c4*4 + 4, f);
      }
      h2[tid] = lrelu(aA + aB);
    }
    __syncthreads();
    // stage4 (t0..127): Z = psconv2 @ h2 + b  (dot256, 4 acc)
    // stage6 (t128..255): Y = conv2 @ hy + b  (dot64, 2 acc)
    if (tid < 128){
      int r = tid;
      float aA = ldin(bps2, r, f), aB = 0.f, aC = 0.f, aD = 0.f;
      #pragma unroll 8
      for (int c4=0; c4<64; c4+=4){
        aA += dot4i(wps2, r*256 + c4*4,     h2 + c4*4,      f);
        aB += dot4i(wps2, r*256 + (c4+1)*4, h2 + c4*4 + 4,  f);
        aC += dot4i(wps2, r*256 + (c4+2)*4, h2 + c4*4 + 8,  f);
        aD += dot4i(wps2, r*256 + (c4+3)*4, h2 + c4*4 + 12, f);
      }
      g_Zw[(size_t)p*128 + r] = (aA + aB) + (aC + aD);
    } else {
      int r = tid - 128;
      float aA = ldin(bc2, r, f), aB = 0.f;
      #pragma unroll 8
      for (int c4=0; c4<16; c4+=2){
        aA += dot4i(wc2, r*64 + c4*4,     hy + c4*4,     f);
        aB += dot4i(wc2, r*64 + (c4+1)*4, hy + c4*4 + 4, f);
      }
      g_Yw[(size_t)p*128 + r] = aA + aB;
    }
  }
}

// kB: FOUR points per block (125 blocks): deterministic denominator reduce +
// weighted gather-mean + fc chain -> out. fc weights converted inline.
__global__ __launch_bounds__(256) void kB(
    const void* imf, const void* wfc1, const void* bfc1,
    const void* wfc2, const void* bfc2, const void* wfc, const void* bfc,
    void* outv)
{
  __shared__ __align__(16) float sm[2312];
  __shared__ int sflag;
  float* sb1 = sm;              // [4][256] : [sf | cf]
  float* sb2 = sm + 1024;       // [4][160] : [sfp | imf]
  float* sg  = sm + 1664;       // [4][128] : lrelu([f2 ; f1])
  float* swa = sm + 2176;       // [4][8]
  float* swb = sm + 2208;       // [4][8]
  int* sia = (int*)(sm + 2240); // [4][8]
  int* sib = (int*)(sm + 2272); // [4][8]
  float* sden = sm + 2304;      // 2
  const int tid = threadIdx.x;
  const int p0 = blockIdx.x*4;
  const int f = detect_f32(imf, tid, &sflag);
  // ---- denominators: fixed-order reduce of 125 partials each (deterministic) ----
  if (tid < 64){
    float vA = (tid < 125) ? g_bsumA[tid] : 0.f;
    float vB = (tid < 125) ? g_bsumB[tid] : 0.f;
    if (tid + 64 < 125){ vA += g_bsumA[tid+64]; vB += g_bsumB[tid+64]; }
    #pragma unroll
    for (int off = 32; off; off >>= 1){
      vA += __shfl_xor(vA, off);
      vB += __shfl_xor(vB, off);
    }
    if (tid == 0){ sden[0] = vA; sden[1] = vB; }
  }
  // ---- staging (disjoint tid ranges; barrier below covers all) ----
  if (tid >= 64 && tid < 96){
    int t = tid - 64, pt = t >> 3, j = t & 7, p = p0 + pt;
    sia[t] = clampi(g_inds[p*8 + j]);
    sib[t] = clampi(g_inds_tc[p*8 + j]);
  }
  {
    int r = tid & 127, pg = (tid >> 7)*2;
    sb1[pg*256 + 128 + r]     = g_cfw[(size_t)(p0+pg)*128 + r];
    sb1[(pg+1)*256 + 128 + r] = g_cfw[(size_t)(p0+pg+1)*128 + r];
  }
  if (tid >= 96 && tid < 224){
    int t = tid - 96, pt = t >> 5, ch = t & 31;
    sb2[pt*160 + 128 + ch] = ldin(imf, ch*NN + p0 + pt, f);
  }
  __syncthreads();
  if (tid < 32){
    int pt = tid >> 3, j = tid & 7, p = p0 + pt;
    swa[tid] = g_logA[p*8 + j] / sden[0];
    swb[tid] = g_logB[p*8 + j] / sden[1];
  }
  __syncthreads();
  // ---- gather-mean: each thread does row r for 2 points, sf and sfp ----
  {
    int r = tid & 127, pg = (tid >> 7)*2;
    #pragma unroll 2
    for (int q = pg; q < pg+2; ++q){
      float acc = 0.f;
      #pragma unroll
      for (int j=0;j<8;++j) acc += swa[q*8+j] * g_Yw[(size_t)sia[q*8+j]*128 + r];
      sb1[q*256 + r] = acc * 0.125f;
      float acp = 0.f;
      #pragma unroll
      for (int j=0;j<8;++j) acp += swb[q*8+j] * g_Zw[(size_t)sib[q*8+j]*128 + r];
      sb2[q*160 + r] = acp * 0.125f;
    }
  }
  __syncthreads();
  // ---- fc1 (dot256, 4 acc) then fc2 (dot160, 2 acc): row=tid&63, pt=tid>>6 ----
  {
    int r = tid & 63, pt = tid >> 6;
    const float* b1 = sb1 + pt*256;
    float aA = ldin(bfc1, r, f), aB = 0.f, aC = 0.f, aD = 0.f;
    #pragma unroll 8
    for (int c4=0; c4<64; c4+=4){
      aA += dot4i(wfc1, r*256 + c4*4,     b1 + c4*4,      f);
      aB += dot4i(wfc1, r*256 + (c4+1)*4, b1 + c4*4 + 4,  f);
      aC += dot4i(wfc1, r*256 + (c4+2)*4, b1 + c4*4 + 8,  f);
      aD += dot4i(wfc1, r*256 + (c4+3)*4, b1 + c4*4 + 12, f);
    }
    sg[pt*128 + 64 + r] = lrelu((aA + aB) + (aC + aD));
    const float* b2s = sb2 + pt*160;
    float cA = ldin(bfc2, r, f), cB = 0.f;
    #pragma unroll 8
    for (int c4=0; c4<40; c4+=2){
      cA += dot4i(wfc2, r*160 + c4*4,     b2s + c4*4,     f);
      cB += dot4i(wfc2, r*160 + (c4+1)*4, b2s + c4*4 + 4, f);
    }
    sg[pt*128 + r] = lrelu(cA + cB);
  }
  __syncthreads();
  // ---- out = wfc @ g + b (dot128, 2 acc): row=tid&63, pt=tid>>6 ----
  {
    int r = tid & 63, pt = tid >> 6, p = p0 + pt;
    const float* gg = sg + pt*128;
    float aA = ldin(bfc, r, f), aB = 0.f;
    #pragma unroll 8
    for (int c4=0; c4<32; c4+=2){
      aA += dot4i(wfc, r*128 + c4*4,     gg + c4*4,     f);
      aB += dot4i(wfc, r*128 + (c4+1)*4, gg + c4*4 + 4, f);
    }
    float a = aA + aB;
    if (f) ((float*)outv)[r*NN + p] = a;
    else   ((us*)outv)[r*NN + p] = f2b(a);
  }
}

extern "C" void kernel_launch(void* const* d_in, const int* in_sizes, int n_in,
                              void* d_out, int out_size, void* d_ws, size_t ws_size,
                              hipStream_t stream)
{
  (void)d_ws; (void)ws_size; (void)in_sizes; (void)n_in; (void)out_size;
  kA<<<750, 256, 0, stream>>>(
    d_in[0], d_in[1], d_in[2],
    d_in[3], d_in[4], d_in[5], d_in[6],
    d_in[7], d_in[8], d_in[9], d_in[10],
    d_in[11], d_in[12], d_in[13], d_in[14]);
  kB<<<125, 256, 0, stream>>>(
    d_in[0], d_in[15], d_in[16], d_in[17], d_in[18], d_in[19], d_in[20],
    d_out);
}

// Round 6
// 132.727 us; speedup vs baseline: 1.8994x; 1.8994x over previous
//
#include <hip/hip_runtime.h>

#define NN 500
#define SLOPEC 0.01f

typedef unsigned short us;
typedef unsigned int u32;
typedef unsigned long long u64;

// ---- canonical fp32 copies of all inputs + scratch, as device globals ----
// (16B-aligned by construction: safe for float4 loads. Harness input buffers
//  are NOT guaranteed 16B-aligned — inputs only ever read with scalar loads in k0.
//  Round-5 lesson: inline bf16 convert in consumers = VGPR 136 / 2x loads / 2.5x
//  slower. The fp32 staging copy is load-bearing.)
__device__ __align__(16) float g_imf[16000];
__device__ __align__(16) float g_c[1504];
__device__ __align__(16) float g_ct[1504];
__device__ __align__(16) float g_wc1[2048];
__device__ __align__(16) float g_bc1[64];
__device__ __align__(16) float g_wc2[8192];
__device__ __align__(16) float g_bc2[128];
__device__ __align__(16) float g_wps1[32768];
__device__ __align__(16) float g_bps1[256];
__device__ __align__(16) float g_wps2[32768];
__device__ __align__(16) float g_bps2[128];
__device__ __align__(16) float g_wp1[192];
__device__ __align__(16) float g_bp1[64];
__device__ __align__(16) float g_wp2[8192];
__device__ __align__(16) float g_bp2[128];
__device__ __align__(16) float g_wfc1[16384];
__device__ __align__(16) float g_bfc1[64];
__device__ __align__(16) float g_wfc2[10240];
__device__ __align__(16) float g_bfc2[64];
__device__ __align__(16) float g_wfc[8192];
__device__ __align__(16) float g_bfc[64];

__device__ __align__(16) float g_cfw[NN*128];
__device__ __align__(16) float g_Yw[NN*128];
__device__ __align__(16) float g_Zw[NN*128];
__device__ __align__(16) float g_logA[4000];   // exp(-dist) numerators (k1)
__device__ __align__(16) float g_logB[4000];
__device__ int   g_inds[4000];
__device__ int   g_inds_tc[4000];
__device__ int   g_isf32;
// per-KNN-block softmax-denominator partials: plain deterministic stores in k1
// (125 used per direction), fixed-order reduce in k3. No atomics, no zeroing.
__device__ __align__(16) float g_bsumA[128];
__device__ __align__(16) float g_bsumB[128];

__device__ __forceinline__ float b2f(us u){ return __uint_as_float(((u32)u)<<16); }
__device__ __forceinline__ us f2b(float f){
  u32 u = __float_as_uint(f);
  u32 r = u + 0x7fffu + ((u>>16)&1u);
  return (us)(r>>16);
}
__device__ __forceinline__ float lrelu(float x){ return x >= 0.f ? x : SLOPEC*x; }
__device__ __forceinline__ float dot4(const float4 w, const float* h){
  return w.x*h[0] + w.y*h[1] + w.z*h[2] + w.w*h[3];
}
__device__ __forceinline__ int clampi(int v){ return v < 0 ? 0 : (v >= NN ? NN-1 : v); }

// K0: detect input dtype (fp32 vs bf16) from img_feat bit patterns, then
// convert every input into canonical fp32 device-global arrays (scalar loads).
__global__ __launch_bounds__(256) void k0(
    const void* in0, const void* in1, const void* in2, const void* in3,
    const void* in4, const void* in5, const void* in6, const void* in7,
    const void* in8, const void* in9, const void* in10, const void* in11,
    const void* in12, const void* in13, const void* in14, const void* in15,
    const void* in16, const void* in17, const void* in18, const void* in19,
    const void* in20)
{
  __shared__ int sflag;
  const int tid = threadIdx.x;
  if (tid < 64){
    const us* u = (const us*)in0;
    int cnt = 0;
    #pragma unroll
    for (int j = 0; j < 8; ++j){
      us v = u[2*(tid*8+j)];          // even us-index: fp32 low-halves if fp32
      int e = (v >> 7) & 0xff;
      cnt += (e >= 143);              // |x| >= 2^16 as bf16: impossible for real data
    }
    #pragma unroll
    for (int off = 32; off; off >>= 1) cnt += __shfl_xor(cnt, off);
    if (tid == 0){ sflag = (cnt > 16); g_isf32 = (cnt > 16); }
  }
  __syncthreads();
  const int isf32 = sflag;
  const int g0 = blockIdx.x*256 + tid;
  const int gs = gridDim.x*256;
  #define CVT(src, dst, n) \
    for (int i = g0; i < (n); i += gs) \
      dst[i] = isf32 ? ((const float*)(src))[i] : b2f(((const us*)(src))[i]);
  CVT(in0,  g_imf, 16000)
  CVT(in1,  g_c,   1500)
  CVT(in2,  g_ct,  1500)
  CVT(in3,  g_wc1, 2048)
  CVT(in4,  g_bc1, 64)
  CVT(in5,  g_wc2, 8192)
  CVT(in6,  g_bc2, 128)
  CVT(in7,  g_wps1,32768)
  CVT(in8,  g_bps1,256)
  CVT(in9,  g_wps2,32768)
  CVT(in10, g_bps2,128)
  CVT(in11, g_wp1, 192)
  CVT(in12, g_bp1, 64)
  CVT(in13, g_wp2, 8192)
  CVT(in14, g_bp2, 128)
  CVT(in15, g_wfc1,16384)
  CVT(in16, g_bfc1,64)
  CVT(in17, g_wfc2,10240)
  CVT(in18, g_bfc2,64)
  CVT(in19, g_wfc, 8192)
  CVT(in20, g_bfc, 64)
  #undef CVT
}

// K1: blocks 0..249   = KNN (1 query per wave, 4/block) + exp(-dist) emission
//                       + deterministic per-block denominator partial store.
//     blocks 250..749 = per-point conv chains, ONE point per block
//                       (round-0-proven parallelism, round-3-proven multi-acc).
__global__ __launch_bounds__(256) void k1()
{
  __shared__ __align__(16) float sm[1504];
  __shared__ float s_wsum[4];
  const int tid = threadIdx.x;
  const int b = blockIdx.x;
  if (b < 250) {
    // ---------------- KNN + exp numerators ----------------
    const int dir = (b >= 125);            // 0: query=c, ref=ct ; 1: query=ct, ref=c
    const float* refp = dir ? g_c : g_ct;
    const float* qp   = dir ? g_ct : g_c;
    int* outp = dir ? g_inds_tc : g_inds;
    float* logp = dir ? g_logB : g_logA;
    for (int e = tid; e < 1500; e += 256) sm[e] = refp[e];
    __syncthreads();
    const int lane = tid & 63;
    const int wv = tid >> 6;
    const int q = b*4 + wv;
    const int qi = q - (dir ? 500 : 0);
    float qx = qp[qi*3+0], qy = qp[qi*3+1], qz = qp[qi*3+2];
    // exact numpy op order: sum(q^2) - 2*dot + sum(r^2)
    float sq = __fadd_rn(__fadd_rn(__fmul_rn(qx,qx),__fmul_rn(qy,qy)),__fmul_rn(qz,qz));
    const u64 SENT = 0xFFFFFFFF00000000ull;   // sentinel carries valid idx 0
    u64 a0=SENT,a1=SENT,a2=SENT,a3=SENT,a4=SENT,a5=SENT,a6=SENT,a7=SENT;
    for (int j = lane; j < NN; j += 64){
      float rx = sm[j*3+0], ry = sm[j*3+1], rz = sm[j*3+2];
      float dt = __fadd_rn(__fadd_rn(__fmul_rn(qx,rx),__fmul_rn(qy,ry)),__fmul_rn(qz,rz));
      float sr = __fadd_rn(__fadd_rn(__fmul_rn(rx,rx),__fmul_rn(ry,ry)),__fmul_rn(rz,rz));
      float d2 = __fadd_rn(__fsub_rn(sq, __fmul_rn(2.f,dt)), sr);
      u32 fb = __float_as_uint(d2);
      fb = (fb & 0x80000000u) ? ~fb : (fb | 0x80000000u);   // monotone float->uint
      u64 key = ((u64)fb << 32) | (u32)j;
      if (key < a0){ u64 t=a0; a0=key; key=t; }
      if (key < a1){ u64 t=a1; a1=key; key=t; }
      if (key < a2){ u64 t=a2; a2=key; key=t; }
      if (key < a3){ u64 t=a3; a3=key; key=t; }
      if (key < a4){ u64 t=a4; a4=key; key=t; }
      if (key < a5){ u64 t=a5; a5=key; key=t; }
      if (key < a6){ u64 t=a6; a6=key; key=t; }
      if (key < a7){ u64 t=a7; a7=key; key=t; }
    }
    float wsum = 0.f;
    #pragma unroll
    for (int r8 = 0; r8 < 8; ++r8){
      u64 m = a0;
      #pragma unroll
      for (int off = 32; off; off >>= 1){
        u64 o = __shfl_xor(m, off);
        if (o < m) m = o;
      }
      bool mine = (a0 == m);
      a0 = mine ? a1 : a0;  a1 = mine ? a2 : a1;  a2 = mine ? a3 : a2;
      a3 = mine ? a4 : a3;  a4 = mine ? a5 : a4;  a5 = mine ? a6 : a5;
      a6 = mine ? a7 : a6;  a7 = mine ? SENT : a7;
      if (lane == 0){
        int idx = (int)(m & 0xffffffffu);
        outp[qi*8 + r8] = idx;
        // softmax numerator exp(-dist), reference dist order
        float rx = sm[idx*3+0], ry = sm[idx*3+1], rz = sm[idx*3+2];
        float dx = __fsub_rn(qx,rx), dy = __fsub_rn(qy,ry), dz = __fsub_rn(qz,rz);
        float s2 = __fadd_rn(__fadd_rn(__fmul_rn(dx,dx),__fmul_rn(dy,dy)),__fmul_rn(dz,dz));
        float v = expf(-sqrtf(s2));   // in [4.5e-5,1]: shift-free safe
        logp[qi*8 + r8] = v;
        wsum += v;
      }
    }
    if (lane == 0) s_wsum[wv] = wsum;
    __syncthreads();
    if (tid == 0){
      float bs = (s_wsum[0] + s_wsum[1]) + (s_wsum[2] + s_wsum[3]);
      (dir ? g_bsumB : g_bsumA)[dir ? (b-125) : b] = bs;   // plain store, no atomic
    }
  } else {
    // ---------------- per-point chain, one point ----------------
    const int p = b - 250;
    float* sx  = sm;          // 3   (c column)
    float* sxi = sm + 4;      // 32  (imf column)
    float* h1  = sm + 64;     // 64
    float* cf  = sm + 128;    // 128
    float* h2  = sm + 256;    // 256
    float* hy  = sm + 512;    // 64
    if (tid < 3)  sx[tid] = g_c[p*3 + tid];
    if (tid >= 32 && tid < 64) sxi[tid-32] = g_imf[(tid-32)*NN + p];
    __syncthreads();
    // stage1: h1 = lrelu(pconv1 @ x + b)   (threads 0..63)
    if (tid < 64){
      float acc = g_bp1[tid];
      acc += g_wp1[tid*3+0]*sx[0];
      acc += g_wp1[tid*3+1]*sx[1];
      acc += g_wp1[tid*3+2]*sx[2];
      h1[tid] = lrelu(acc);
    }
    __syncthreads();
    // stage2 (t0..127): cf = pconv2 @ h1 + b  (dot64, 2 acc)
    // stage5 (t128..191): hy = lrelu(conv1 @ imf + b)  (dot32, 2 acc)
    if (tid < 128){
      int r = tid;
      float aA = g_bp2[r], aB = 0.f;
      const float4* wrow = (const float4*)(g_wp2 + (size_t)r*64);
      #pragma unroll 8
      for (int c4=0; c4<16; c4+=2){
        aA += dot4(wrow[c4],   h1 + c4*4);
        aB += dot4(wrow[c4+1], h1 + c4*4 + 4);
      }
      float acc = aA + aB;
      cf[r] = acc;
      g_cfw[(size_t)p*128 + r] = acc;
    } else if (tid < 192){
      int r = tid - 128;
      float aA = g_bc1[r], aB = 0.f;
      const float4* wrow = (const float4*)(g_wc1 + (size_t)r*32);
      #pragma unroll 4
      for (int c4=0; c4<8; c4+=2){
        aA += dot4(wrow[c4],   sxi + c4*4);
        aB += dot4(wrow[c4+1], sxi + c4*4 + 4);
      }
      hy[r] = lrelu(aA + aB);
    }
    __syncthreads();
    // stage3 (all 256): h2 = lrelu(psconv1 @ cf + b)  (dot128, 2 acc)
    {
      float aA = g_bps1[tid], aB = 0.f;
      const float4* wrow = (const float4*)(g_wps1 + (size_t)tid*128);
      #pragma unroll 8
      for (int c4=0; c4<32; c4+=2){
        aA += dot4(wrow[c4],   cf + c4*4);
        aB += dot4(wrow[c4+1], cf + c4*4 + 4);
      }
      h2[tid] = lrelu(aA + aB);
    }
    __syncthreads();
    // stage4 (t0..127): Z = psconv2 @ h2 + b  (dot256, 4 acc)
    // stage6 (t128..255): Y = conv2 @ hy + b  (dot64, 2 acc)
    if (tid < 128){
      int r = tid;
      float aA = g_bps2[r], aB = 0.f, aC = 0.f, aD = 0.f;
      const float4* wrow = (const float4*)(g_wps2 + (size_t)r*256);
      #pragma unroll 8
      for (int c4=0; c4<64; c4+=4){
        aA += dot4(wrow[c4],   h2 + c4*4);
        aB += dot4(wrow[c4+1], h2 + c4*4 + 4);
        aC += dot4(wrow[c4+2], h2 + c4*4 + 8);
        aD += dot4(wrow[c4+3], h2 + c4*4 + 12);
      }
      g_Zw[(size_t)p*128 + r] = (aA + aB) + (aC + aD);
    } else {
      int r = tid - 128;
      float aA = g_bc2[r], aB = 0.f;
      const float4* wrow = (const float4*)(g_wc2 + (size_t)r*64);
      #pragma unroll 8
      for (int c4=0; c4<16; c4+=2){
        aA += dot4(wrow[c4],   hy + c4*4);
        aB += dot4(wrow[c4+1], hy + c4*4 + 4);
      }
      g_Yw[(size_t)p*128 + r] = aA + aB;
    }
  }
}

// K3: ONE point per block (500 blocks): deterministic denominator reduce of
// k1's 125 partials (replaces round-0's per-block 8000-float redundant sum),
// then weighted gather-mean + fc chain -> out (round-3-proven multi-acc).
__global__ __launch_bounds__(256) void k3(void* outv)
{
  __shared__ __align__(16) float sm[600];
  float* sb1 = sm;          // 256 : [sf | cf]
  float* sb2 = sm + 256;    // 160 : [sfp | imf]
  float* sg  = sm + 416;    // 128 : lrelu([f2 ; f1])
  float* swa = sm + 544;    // 8
  float* swb = sm + 552;    // 8
  int* sia = (int*)(sm + 560);  // 8
  int* sib = (int*)(sm + 568);  // 8
  float* sden = sm + 576;   // 2
  const int tid = threadIdx.x;
  const int lane = tid & 63;
  const int p = blockIdx.x;
  const int of32 = g_isf32;
  // ---- denominators: fixed-order reduce of 125 partials (deterministic) ----
  if (tid < 64){
    float vA = g_bsumA[tid];
    float vB = g_bsumB[tid];
    if (tid + 64 < 125){ vA += g_bsumA[tid+64]; vB += g_bsumB[tid+64]; }
    #pragma unroll
    for (int off = 32; off; off >>= 1){
      vA += __shfl_xor(vA, off);
      vB += __shfl_xor(vB, off);
    }
    if (tid == 0){ sden[0] = vA; sden[1] = vB; }
  }
  // ---- staging (disjoint tid ranges; barrier below covers all) ----
  if (tid >= 224){
    int t = tid - 224;               // 0..31
    if (t < 8){
      sia[t] = clampi(g_inds[p*8 + t]);
      sib[t] = clampi(g_inds_tc[p*8 + t]);
    }
  }
  if (tid >= 64 && tid < 192) sb1[128 + (tid-64)] = g_cfw[(size_t)p*128 + (tid-64)];
  if (tid >= 192 && tid < 224) sb2[128 + (tid-192)] = g_imf[(tid-192)*NN + p];
  __syncthreads();
  if (tid < 8){
    swa[tid] = g_logA[p*8 + tid] / sden[0];
    swb[tid] = g_logB[p*8 + tid] / sden[1];
  }
  __syncthreads();
  // gather-mean: t0..127 -> sf (from Y), t128..255 -> sfp (from Z)
  if (tid < 128){
    int r = tid;
    float acc = 0.f;
    #pragma unroll
    for (int j=0;j<8;++j) acc += swa[j] * g_Yw[(size_t)sia[j]*128 + r];
    sb1[r] = acc * 0.125f;
  } else {
    int r = tid - 128;
    float acc = 0.f;
    #pragma unroll
    for (int j=0;j<8;++j) acc += swb[j] * g_Zw[(size_t)sib[j]*128 + r];
    sb2[r] = acc * 0.125f;
  }
  __syncthreads();
  // f1 (t0..63, dot256, 4 acc) ; f2 (t64..127, dot160, 2 acc); g = lrelu([f2 ; f1])
  if (tid < 64){
    int r = tid;
    float aA = g_bfc1[r], aB = 0.f, aC = 0.f, aD = 0.f;
    const float4* w1 = (const float4*)(g_wfc1 + (size_t)r*256);
    #pragma unroll 8
    for (int c4=0; c4<64; c4+=4){
      aA += dot4(w1[c4],   sb1 + c4*4);
      aB += dot4(w1[c4+1], sb1 + c4*4 + 4);
      aC += dot4(w1[c4+2], sb1 + c4*4 + 8);
      aD += dot4(w1[c4+3], sb1 + c4*4 + 12);
    }
    sg[64 + r] = lrelu((aA + aB) + (aC + aD));
  } else if (tid < 128){
    int r = tid - 64;
    float aA = g_bfc2[r], aB = 0.f;
    const float4* w2 = (const float4*)(g_wfc2 + (size_t)r*160);
    #pragma unroll 8
    for (int c4=0; c4<40; c4+=2){
      aA += dot4(w2[c4],   sb2 + c4*4);
      aB += dot4(w2[c4+1], sb2 + c4*4 + 4);
    }
    sg[r] = lrelu(aA + aB);
  }
  __syncthreads();
  // out = wfc @ g + b (t0..63, dot128, 2 acc)
  if (tid < 64){
    int r = tid;
    float aA = g_bfc[r], aB = 0.f;
    const float4* w3 = (const float4*)(g_wfc + (size_t)r*128);
    #pragma unroll 8
    for (int c4=0; c4<32; c4+=2){
      aA += dot4(w3[c4],   sg + c4*4);
      aB += dot4(w3[c4+1], sg + c4*4 + 4);
    }
    float a = aA + aB;
    if (of32) ((float*)outv)[r*NN + p] = a;
    else      ((us*)outv)[r*NN + p] = f2b(a);
  }
}

extern "C" void kernel_launch(void* const* d_in, const int* in_sizes, int n_in,
                              void* d_out, int out_size, void* d_ws, size_t ws_size,
                              hipStream_t stream)
{
  (void)d_ws; (void)ws_size; (void)in_sizes; (void)n_in; (void)out_size;
  k0<<<256, 256, 0, stream>>>(
    d_in[0], d_in[1], d_in[2], d_in[3], d_in[4], d_in[5], d_in[6],
    d_in[7], d_in[8], d_in[9], d_in[10], d_in[11], d_in[12], d_in[13],
    d_in[14], d_in[15], d_in[16], d_in[17], d_in[18], d_in[19], d_in[20]);
  k1<<<750, 256, 0, stream>>>();
  k3<<<500, 256, 0, stream>>>(d_out);
}